// Round 10
// baseline (380.858 us; speedup 1.0000x reference)
//
#include <hip/hip_runtime.h>
#include <hip/hip_bf16.h>
#include <stdint.h>

#define B_ 4
#define T_ 2048
#define D_ 1024
#define H_ 16
#define HD_ 64

// softmax computed as 2^(s*log2e): log2(e)/8 folded into Q projection scale
#define QSCALE 0.1803368801111244f

typedef __bf16 bf16_t;
typedef __bf16 bf16x8 __attribute__((ext_vector_type(8)));
typedef __bf16 bf16x4 __attribute__((ext_vector_type(4)));
typedef float f32x4 __attribute__((ext_vector_type(4)));

__device__ __forceinline__ f32x4 mfma16(bf16x8 a, bf16x8 b, f32x4 c) {
  return __builtin_amdgcn_mfma_f32_16x16x32_bf16(a, b, c, 0, 0, 0);
}

__device__ __forceinline__ void gload_lds16(const bf16_t* g, bf16_t* l) {
  __builtin_amdgcn_global_load_lds(
      (const __attribute__((address_space(1))) unsigned int*)g,
      (__attribute__((address_space(3))) unsigned int*)l, 16, 0, 0);
}

__device__ __forceinline__ float exp2g(float x) {
  return __builtin_amdgcn_exp2f(x);
}

// ---------------------------------------------------------------------------
// convert x fp32 -> bf16 (linear)
// ---------------------------------------------------------------------------
__global__ __launch_bounds__(256) void conv_x(const float* __restrict__ x,
                                              bf16_t* __restrict__ xb) {
  size_t i = ((size_t)blockIdx.x * 256 + threadIdx.x) * 8;
  float4 a = *(const float4*)(x + i);
  float4 b = *(const float4*)(x + i + 4);
  bf16x8 v;
  v[0] = (bf16_t)a.x; v[1] = (bf16_t)a.y; v[2] = (bf16_t)a.z; v[3] = (bf16_t)a.w;
  v[4] = (bf16_t)b.x; v[5] = (bf16_t)b.y; v[6] = (bf16_t)b.z; v[7] = (bf16_t)b.w;
  *(bf16x8*)(xb + i) = v;
}

// ---------------------------------------------------------------------------
// convert + transpose W[k][n] fp32 -> Wt[n][k] bf16 (64x64 tiles via LDS)
// blockIdx.z selects which of the 3 weight matrices (one launch).
// ---------------------------------------------------------------------------
__global__ __launch_bounds__(256) void conv_wt3(
    const float* __restrict__ Wq, const float* __restrict__ Wk,
    const float* __restrict__ Wv, bf16_t* __restrict__ WtAll) {
  __shared__ float Ls[64][65];
  const int tid = threadIdx.x;
  const int z = blockIdx.z;
  const float* W = (z == 0) ? Wq : (z == 1) ? Wk : Wv;
  bf16_t* Wt = WtAll + (size_t)z * 1024 * D_;
  const int k0 = blockIdx.y * 64, n0 = blockIdx.x * 64;
  const int rr = tid >> 4, cc = (tid & 15) * 4;
#pragma unroll
  for (int it = 0; it < 4; ++it) {
    int r = rr + it * 16;
    float4 v = *(const float4*)(W + (size_t)(k0 + r) * D_ + n0 + cc);
    Ls[r][cc] = v.x; Ls[r][cc + 1] = v.y; Ls[r][cc + 2] = v.z; Ls[r][cc + 3] = v.w;
  }
  __syncthreads();
#pragma unroll
  for (int it = 0; it < 4; ++it) {
    int nl = rr + it * 16;
    bf16x4 o;
    o[0] = (bf16_t)Ls[cc][nl];     o[1] = (bf16_t)Ls[cc + 1][nl];
    o[2] = (bf16_t)Ls[cc + 2][nl]; o[3] = (bf16_t)Ls[cc + 3][nl];
    *(bf16x4*)(Wt + (size_t)(n0 + nl) * D_ + k0 + cc) = o;
  }
}

// ---------------------------------------------------------------------------
// fused QKV GEMM (round-5 structure, measured best): A=xb[8192][1024],
// Bt=WtAll[3072][1024]. 128x128 tiles, BK=64, global_load_lds staging.
// 1536 blocks; each XCD owns 8 contiguous m-panels x all 24 n-panels.
// mode = nb>>3: 0->Q (scaled QSCALE), 1->K, 2->V transposed.
// ---------------------------------------------------------------------------
__global__ __launch_bounds__(256) void gemm_qkv(
    const bf16_t* __restrict__ A, const bf16_t* __restrict__ Bt,
    const float* __restrict__ bq, const float* __restrict__ bk,
    const float* __restrict__ bv,
    bf16_t* __restrict__ Qo, bf16_t* __restrict__ Ko, bf16_t* __restrict__ Vo)
{
  __shared__ __align__(16) bf16_t As[128 * 64];
  __shared__ __align__(16) bf16_t Bs[128 * 64];
  const int tid = threadIdx.x, lane = tid & 63, wv = tid >> 6;
  const int wr = wv >> 1, wc = wv & 1;
  const int wg = blockIdx.x;
  const int lin = (wg & 7) * 192 + (wg >> 3);   // 1536 = 8 xcd * 192
  const int mb = lin / 24, nb = lin - mb * 24;  // 64 mb x 24 nb
  const int m0 = mb * 128, n0 = nb * 128;
  const int mode = nb >> 3;                     // 0..2
  const int lr = lane & 15, lg = lane >> 4;
  const int srow = wv * 8 + (lane >> 3);
  const int scol = (lane & 7) * 8;

  f32x4 acc[4][4] = {};

  for (int k0 = 0; k0 < D_; k0 += 64) {
    __syncthreads();
#pragma unroll
    for (int i = 0; i < 4; ++i) {
      gload_lds16(A + (size_t)(m0 + i * 32 + srow) * D_ + k0 + scol,
                  &As[(i * 32 + wv * 8) * 64]);
      gload_lds16(Bt + (size_t)(n0 + i * 32 + srow) * D_ + k0 + scol,
                  &Bs[(i * 32 + wv * 8) * 64]);
    }
    __syncthreads();

#pragma unroll
    for (int ks = 0; ks < 2; ++ks) {
      bf16x8 af[4], bfr[4];
#pragma unroll
      for (int i = 0; i < 4; ++i)
        af[i] = *(const bf16x8*)&As[(wr * 64 + i * 16 + lr) * 64 + ks * 32 + lg * 8];
#pragma unroll
      for (int j = 0; j < 4; ++j)
        bfr[j] = *(const bf16x8*)&Bs[(wc * 64 + j * 16 + lr) * 64 + ks * 32 + lg * 8];
      if (mode < 2) {
#pragma unroll
        for (int i = 0; i < 4; ++i)
#pragma unroll
          for (int j = 0; j < 4; ++j)
            acc[i][j] = mfma16(af[i], bfr[j], acc[i][j]);
      } else {
#pragma unroll
        for (int i = 0; i < 4; ++i)
#pragma unroll
          for (int j = 0; j < 4; ++j)
            acc[i][j] = mfma16(bfr[j], af[i], acc[i][j]);
      }
    }
  }

  if (mode == 2) {
    const int nl0 = n0 - 2048;
#pragma unroll
    for (int i = 0; i < 4; ++i) {
      int m = m0 + wr * 64 + i * 16 + lr;
      int b = m >> 11, t = m & (T_ - 1);
#pragma unroll
      for (int j = 0; j < 4; ++j)
#pragma unroll
        for (int r = 0; r < 4; ++r) {
          int n = nl0 + wc * 64 + j * 16 + lg * 4 + r;
          int h = n >> 6, d = n & 63;
          float val = acc[i][j][r] + bv[n];
          Vo[((size_t)(b * H_ + h) * HD_ + d) * T_ + t] = (bf16_t)val;
        }
    }
  } else {
    bf16_t* out = mode ? Ko : Qo;
    const float* bias = mode ? bk : bq;
    const float scale = mode ? 1.0f : QSCALE;
    const int nl0 = n0 - mode * 1024;
#pragma unroll
    for (int j = 0; j < 4; ++j) {
      int n = nl0 + wc * 64 + j * 16 + lr;
      float bval = bias[n];
      int h = n >> 6, d = n & 63;
#pragma unroll
      for (int i = 0; i < 4; ++i)
#pragma unroll
        for (int r = 0; r < 4; ++r) {
          int m = m0 + wr * 64 + i * 16 + lg * 4 + r;
          int b = m >> 11, t = m & (T_ - 1);
          float val = (acc[i][j][r] + bval) * scale;
          out[(((size_t)(b * H_ + h)) * T_ + t) * HD_ + d] = (bf16_t)val;
        }
    }
  }
}

// ---------------------------------------------------------------------------
// fallback GEMM (fp32 inputs) — validated round-1/2 structure
// ---------------------------------------------------------------------------
template <int OUT_MODE>
__global__ __launch_bounds__(256) void qkv_gemm_f32(
    const float* __restrict__ x, const float* __restrict__ W,
    const float* __restrict__ bias, bf16_t* __restrict__ out, float scale)
{
  __shared__ bf16_t As[128][40];
  __shared__ bf16_t Bs[128][40];
  const int tid = threadIdx.x, lane = tid & 63, wv = tid >> 6;
  const int wr = wv >> 1, wc = wv & 1;
  const int m0 = blockIdx.y * 128, n0 = blockIdx.x * 128;
  const int lr = lane & 15, lg = lane >> 4;
  f32x4 acc[4][4] = {};
  const int xr = tid >> 3, xc = tid & 7;
  const int wk = tid >> 5, wn = tid & 31;

  for (int k0 = 0; k0 < D_; k0 += 32) {
    __syncthreads();
#pragma unroll
    for (int it = 0; it < 4; ++it) {
      int r = xr + it * 32;
      float4 v = *(const float4*)(x + (size_t)(m0 + r) * D_ + k0 + xc * 4);
      bf16_t* dst = &As[r][xc * 4];
      dst[0] = (bf16_t)v.x; dst[1] = (bf16_t)v.y;
      dst[2] = (bf16_t)v.z; dst[3] = (bf16_t)v.w;
    }
#pragma unroll
    for (int it = 0; it < 4; ++it) {
      int k = wk + it * 8;
      float4 v = *(const float4*)(W + (size_t)(k0 + k) * D_ + n0 + wn * 4);
      Bs[wn * 4 + 0][k] = (bf16_t)v.x;
      Bs[wn * 4 + 1][k] = (bf16_t)v.y;
      Bs[wn * 4 + 2][k] = (bf16_t)v.z;
      Bs[wn * 4 + 3][k] = (bf16_t)v.w;
    }
    __syncthreads();
    bf16x8 af[4], bfr[4];
#pragma unroll
    for (int i = 0; i < 4; ++i) af[i]  = *(const bf16x8*)&As[wr * 64 + i * 16 + lr][lg * 8];
#pragma unroll
    for (int j = 0; j < 4; ++j) bfr[j] = *(const bf16x8*)&Bs[wc * 64 + j * 16 + lr][lg * 8];
#pragma unroll
    for (int i = 0; i < 4; ++i)
#pragma unroll
      for (int j = 0; j < 4; ++j) {
        if (OUT_MODE == 0) acc[i][j] = mfma16(af[i], bfr[j], acc[i][j]);
        else               acc[i][j] = mfma16(bfr[j], af[i], acc[i][j]);
      }
  }

  if (OUT_MODE == 0) {
#pragma unroll
    for (int j = 0; j < 4; ++j) {
      int n = n0 + wc * 64 + j * 16 + lr;
      float bval = bias[n];
      int h = n >> 6, d = n & 63;
#pragma unroll
      for (int i = 0; i < 4; ++i)
#pragma unroll
        for (int r = 0; r < 4; ++r) {
          int m = m0 + wr * 64 + i * 16 + lg * 4 + r;
          int b = m >> 11, t = m & (T_ - 1);
          float val = (acc[i][j][r] + bval) * scale;
          out[(((size_t)(b * H_ + h)) * T_ + t) * HD_ + d] = (bf16_t)val;
        }
    }
  } else {
#pragma unroll
    for (int i = 0; i < 4; ++i) {
      int m = m0 + wr * 64 + i * 16 + lr;
      int b = m >> 11, t = m & (T_ - 1);
#pragma unroll
      for (int j = 0; j < 4; ++j)
#pragma unroll
        for (int r = 0; r < 4; ++r) {
          int n = n0 + wc * 64 + j * 16 + lg * 4 + r;
          int h = n >> 6, d = n & 63;
          float val = acc[i][j][r] + bias[n];
          out[((size_t)(b * H_ + h) * HD_ + d) * T_ + t] = (bf16_t)val;
        }
    }
  }
}

// ---------------------------------------------------------------------------
// attnA v6: explicit in-order pair pipeline. Block = (bh, 128 q), 4 waves x
// 32 q. Two 64-row K-tiles per barrier; one fused body orders the work so
// MFMA drain always has VALU under it:
//   QKT(A) -> QKT(B) -> exp/store(A) -> readP(A) -> PV(A)
//   -> exp/store(B) [overlaps PV(A) drain] -> readP(B) -> PV(B)
// P ping-pong per wave; K 4-buffer rotation; V direct from global Vt[d][t].
// ---------------------------------------------------------------------------
__global__ __launch_bounds__(256, 2) void attnA(
    const bf16_t* __restrict__ Q, const bf16_t* __restrict__ K,
    const bf16_t* __restrict__ Vt, bf16_t* __restrict__ O,
    float* __restrict__ Linv)
{
  __shared__ __align__(16) bf16_t Ks[4][64 * 64];     // 32 KB, pair-rotated
  __shared__ __align__(16) bf16_t Pl[4][2][32 * 64];  // 32 KB, ping-pong
  __shared__ float ltab[4][32];

  const int tid = threadIdx.x, lane = tid & 63, wv = tid >> 6;
  const int lr = lane & 15, lg = lane >> 4;
  // 1024 blocks = 8 xcd * 8 bh * 16 qb
  const int wg = blockIdx.x;
  const int p_ = wg >> 3;
  const int bh = (wg & 7) * 8 + (p_ >> 4);
  const int qb = p_ & 15;
  const int q0 = qb * 128 + wv * 32;
  const int swz = (lr & 7) << 3;
  const int kswz = lr & 7;

  const bf16_t* Qb = Q + (size_t)bh * T_ * HD_;
  const bf16_t* Kb = K + (size_t)bh * T_ * HD_;
  const bf16_t* Vb = Vt + (size_t)bh * HD_ * T_;

  bf16x8 qf0[2], qf1[2];
#pragma unroll
  for (int ks = 0; ks < 2; ++ks) {
    qf0[ks] = *(const bf16x8*)(Qb + (size_t)(q0 + lr) * HD_ + ks * 32 + lg * 8);
    qf1[ks] = *(const bf16x8*)(Qb + (size_t)(q0 + 16 + lr) * HD_ + ks * 32 + lg * 8);
  }

  auto stageK = [&](int buf, int t0) {
    const bf16_t* src = Kb + (size_t)t0 * HD_;
#pragma unroll
    for (int rnd = 0; rnd < 2; ++rnd) {
      const int c = rnd * 256 + tid;
      const int row = c >> 3;
      const int sc16 = (c & 7) ^ (row & 7);
      gload_lds16(src + row * HD_ + sc16 * 8, &Ks[buf][c * 8]);
    }
  };

  float lacc0 = 0.f, lacc1 = 0.f;
  f32x4 oacc[2][4] = {};

  // prologue: stage pair 0
  stageK(0, 0);
  stageK(1, 64);
  __syncthreads();

  for (int p = 0; p < 16; ++p) {
    const int base = (p & 1) ? 2 : 0;
    const int other = base ^ 2;
    if (p < 15) {
      stageK(other,     (2 * p + 2) * 64);
      stageK(other + 1, (2 * p + 3) * 64);
    }
    const bf16_t* KlA = &Ks[base][0];
    const bf16_t* KlB = &Ks[base + 1][0];
    const int t0A = (2 * p) * 64;
    const int t0B = t0A + 64;
    bf16_t* PwA = &Pl[wv][0][0];
    bf16_t* PwB = &Pl[wv][1][0];

    // ---- V fragments for both tiles (issue early, consume at PV) ----
    bf16x8 vfaA[4], vfbA[4], vfaB[4], vfbB[4];
#pragma unroll
    for (int dj = 0; dj < 4; ++dj) {
      const bf16_t* vrow = Vb + (size_t)(dj * 16 + lr) * T_;
      vfaA[dj] = *(const bf16x8*)(vrow + t0A + lg * 8);
      vfbA[dj] = *(const bf16x8*)(vrow + t0A + 32 + lg * 8);
      vfaB[dj] = *(const bf16x8*)(vrow + t0B + lg * 8);
      vfbB[dj] = *(const bf16x8*)(vrow + t0B + 32 + lg * 8);
    }

    // ---- QKT(A): 8 MFMA ----
    f32x4 sA0[4], sA1[4];
#pragma unroll
    for (int tt = 0; tt < 4; ++tt) {
      const int row = tt * 16 + lr;
      bf16x8 kf0 = *(const bf16x8*)&KlA[row * 64 + ((lg ^ kswz) * 8)];
      bf16x8 kf1 = *(const bf16x8*)&KlA[row * 64 + (((4 + lg) ^ kswz) * 8)];
      f32x4 s0 = {}, s1 = {};
      s0 = mfma16(kf0, qf0[0], s0);
      s0 = mfma16(kf1, qf0[1], s0);
      s1 = mfma16(kf0, qf1[0], s1);
      s1 = mfma16(kf1, qf1[1], s1);
      sA0[tt] = s0; sA1[tt] = s1;
    }

    // ---- QKT(B): 8 MFMA (independent; issues while A's drain) ----
    f32x4 sB0[4], sB1[4];
#pragma unroll
    for (int tt = 0; tt < 4; ++tt) {
      const int row = tt * 16 + lr;
      bf16x8 kf0 = *(const bf16x8*)&KlB[row * 64 + ((lg ^ kswz) * 8)];
      bf16x8 kf1 = *(const bf16x8*)&KlB[row * 64 + (((4 + lg) ^ kswz) * 8)];
      f32x4 s0 = {}, s1 = {};
      s0 = mfma16(kf0, qf0[0], s0);
      s0 = mfma16(kf1, qf0[1], s0);
      s1 = mfma16(kf0, qf1[0], s1);
      s1 = mfma16(kf1, qf1[1], s1);
      sB0[tt] = s0; sB1[tt] = s1;
    }

    // ---- exp/pack/store P(A) ----
#pragma unroll
    for (int tt = 0; tt < 4; ++tt) {
      f32x4 e0, e1;
#pragma unroll
      for (int r = 0; r < 4; ++r) {
        e0[r] = exp2g(sA0[tt][r]);
        e1[r] = exp2g(sA1[tt][r]);
        lacc0 += e0[r];
        lacc1 += e1[r];
      }
      const int tb = tt * 16 + lg * 4;
      bf16x4 pk0, pk1;
#pragma unroll
      for (int r = 0; r < 4; ++r) { pk0[r] = (bf16_t)e0[r]; pk1[r] = (bf16_t)e1[r]; }
      *(bf16x4*)&PwA[(lr) * 64 + (tb ^ swz)]      = pk0;
      *(bf16x4*)&PwA[(16 + lr) * 64 + (tb ^ swz)] = pk1;
    }

    // ---- read P(A) fragments, PV(A): 16 MFMA ----
    {
      bf16x8 pf0[2], pf1[2];
#pragma unroll
      for (int ks = 0; ks < 2; ++ks) {
        pf0[ks] = *(const bf16x8*)&PwA[(lr) * 64 + ((ks * 32 + lg * 8) ^ swz)];
        pf1[ks] = *(const bf16x8*)&PwA[(16 + lr) * 64 + ((ks * 32 + lg * 8) ^ swz)];
      }
      __builtin_amdgcn_s_setprio(1);
#pragma unroll
      for (int dj = 0; dj < 4; ++dj) {
        oacc[0][dj] = mfma16(pf0[0], vfaA[dj], oacc[0][dj]);
        oacc[0][dj] = mfma16(pf0[1], vfbA[dj], oacc[0][dj]);
        oacc[1][dj] = mfma16(pf1[0], vfaA[dj], oacc[1][dj]);
        oacc[1][dj] = mfma16(pf1[1], vfbA[dj], oacc[1][dj]);
      }
      __builtin_amdgcn_s_setprio(0);
    }

    // ---- exp/pack/store P(B): VALU overlaps PV(A) drain ----
#pragma unroll
    for (int tt = 0; tt < 4; ++tt) {
      f32x4 e0, e1;
#pragma unroll
      for (int r = 0; r < 4; ++r) {
        e0[r] = exp2g(sB0[tt][r]);
        e1[r] = exp2g(sB1[tt][r]);
        lacc0 += e0[r];
        lacc1 += e1[r];
      }
      const int tb = tt * 16 + lg * 4;
      bf16x4 pk0, pk1;
#pragma unroll
      for (int r = 0; r < 4; ++r) { pk0[r] = (bf16_t)e0[r]; pk1[r] = (bf16_t)e1[r]; }
      *(bf16x4*)&PwB[(lr) * 64 + (tb ^ swz)]      = pk0;
      *(bf16x4*)&PwB[(16 + lr) * 64 + (tb ^ swz)] = pk1;
    }

    // ---- read P(B) fragments, PV(B): 16 MFMA ----
    {
      bf16x8 pf0[2], pf1[2];
#pragma unroll
      for (int ks = 0; ks < 2; ++ks) {
        pf0[ks] = *(const bf16x8*)&PwB[(lr) * 64 + ((ks * 32 + lg * 8) ^ swz)];
        pf1[ks] = *(const bf16x8*)&PwB[(16 + lr) * 64 + ((ks * 32 + lg * 8) ^ swz)];
      }
      __builtin_amdgcn_s_setprio(1);
#pragma unroll
      for (int dj = 0; dj < 4; ++dj) {
        oacc[0][dj] = mfma16(pf0[0], vfaB[dj], oacc[0][dj]);
        oacc[0][dj] = mfma16(pf0[1], vfbB[dj], oacc[0][dj]);
        oacc[1][dj] = mfma16(pf1[0], vfaB[dj], oacc[1][dj]);
        oacc[1][dj] = mfma16(pf1[1], vfbB[dj], oacc[1][dj]);
      }
      __builtin_amdgcn_s_setprio(0);
    }

    __syncthreads();
  }

  // reduce l over the 4 lane-groups sharing q = lr (+16)
  lacc0 += __shfl_xor(lacc0, 16); lacc0 += __shfl_xor(lacc0, 32);
  lacc1 += __shfl_xor(lacc1, 16); lacc1 += __shfl_xor(lacc1, 32);
  const float linv0 = 1.f / lacc0, linv1 = 1.f / lacc1;
  if (lg == 0) {
    ltab[wv][lr] = linv0;
    ltab[wv][16 + lr] = linv1;
    Linv[(size_t)bh * T_ + q0 + lr] = linv0;
    Linv[(size_t)bh * T_ + q0 + 16 + lr] = linv1;
  }
  __syncthreads();

  // normalize + write O[bh, q, d]
#pragma unroll
  for (int qi = 0; qi < 2; ++qi)
#pragma unroll
    for (int dj = 0; dj < 4; ++dj)
#pragma unroll
      for (int r = 0; r < 4; ++r) {
        int ql = qi * 16 + lg * 4 + r;
        float sc = ltab[wv][ql];
        O[((size_t)bh * T_ + q0 + ql) * HD_ + dj * 16 + lr] =
            (bf16_t)(oacc[qi][dj][r] * sc);
      }
}

// ---------------------------------------------------------------------------
// attnB: colsum[b,t] += sum_q 2^(s[q,t]) * Linv[q]  (per head, atomic).
// 1024 blocks = 64 bh x 8 tc x 2 q-splits. K rows in registers. No LDS.
// ---------------------------------------------------------------------------
__global__ __launch_bounds__(256) void attnB(
    const bf16_t* __restrict__ Q, const bf16_t* __restrict__ K,
    const float* __restrict__ Linv, float* __restrict__ colsum)
{
  const int tid = threadIdx.x, lane = tid & 63, wv = tid >> 6;
  const int lr = lane & 15, lg = lane >> 4;
  // 1024 blocks = 8 xcd * 8 bh * (8 tc * 2 qs)
  const int wg = blockIdx.x;
  const int p_ = wg >> 3;
  const int bh = (wg & 7) * 8 + (p_ >> 4);
  const int rem = p_ & 15;
  const int tc = rem >> 1;
  const int qs = rem & 1;
  const int b = bh >> 4;
  const int t0w = tc * 256 + wv * 64;

  const bf16_t* Qb = Q + (size_t)bh * T_ * HD_;
  const bf16_t* Kb = K + (size_t)bh * T_ * HD_;
  const float* Lb = Linv + (size_t)bh * T_;

  bf16x8 kf[4][2];
#pragma unroll
  for (int tt = 0; tt < 4; ++tt)
#pragma unroll
    for (int ks = 0; ks < 2; ++ks)
      kf[tt][ks] = *(const bf16x8*)(Kb + (size_t)(t0w + tt * 16 + lr) * HD_ +
                                    ks * 32 + lg * 8);

  float acc[4][4] = {};   // [tt][r] : t = t0w + tt*16 + 4*lg + r

  const int qlo = qs * (T_ / 2), qhi = qlo + T_ / 2;
  for (int qb = qlo; qb < qhi; qb += 64) {
#pragma unroll
    for (int qt = 0; qt < 4; ++qt) {
      const int q = qb + qt * 16 + lr;
      bf16x8 qv0 = *(const bf16x8*)(Qb + (size_t)q * HD_ + lg * 8);
      bf16x8 qv1 = *(const bf16x8*)(Qb + (size_t)q * HD_ + 32 + lg * 8);
      const float lv = Lb[q];
#pragma unroll
      for (int tt = 0; tt < 4; ++tt) {
        f32x4 s = {};
        __builtin_amdgcn_s_setprio(1);
        s = mfma16(kf[tt][0], qv0, s);
        s = mfma16(kf[tt][1], qv1, s);
        __builtin_amdgcn_s_setprio(0);
#pragma unroll
        for (int r = 0; r < 4; ++r)
          acc[tt][r] = fmaf(exp2g(s[r]), lv, acc[tt][r]);
      }
    }
  }

#pragma unroll
  for (int tt = 0; tt < 4; ++tt)
#pragma unroll
    for (int r = 0; r < 4; ++r) {
      float v = acc[tt][r];
      v += __shfl_xor(v, 1); v += __shfl_xor(v, 2);
      v += __shfl_xor(v, 4); v += __shfl_xor(v, 8);
      acc[tt][r] = v;
    }
  if (lr == 0) {
#pragma unroll
    for (int tt = 0; tt < 4; ++tt)
#pragma unroll
      for (int r = 0; r < 4; ++r)
        atomicAdd(&colsum[b * T_ + t0w + tt * 16 + lg * 4 + r], acc[tt][r]);
  }
}

// ---------------------------------------------------------------------------
// pooling: pre[b, h*64+d] += (1/32768) * sum_{t in chunk} CS[b,t] * O[bh,t,d]
// 512 blocks = 64 bh x 8 t-chunks; PRE zeroed beforehand.
// ---------------------------------------------------------------------------
__global__ __launch_bounds__(256) void pool3(
    const bf16_t* __restrict__ O, const float* __restrict__ CS,
    float* __restrict__ pre)
{
  __shared__ float sm[256];
  const int wg = blockIdx.x;
  const int bh = wg >> 3, tc = wg & 7;
  const int b = bh >> 4, h = bh & 15;
  const int tid = threadIdx.x, d = tid & 63, tg = tid >> 6;
  const bf16_t* Ob = O + (size_t)bh * T_ * HD_ + (size_t)tc * 256 * HD_;
  const float* cw = CS + b * T_ + tc * 256;
  float acc = 0.f;
  for (int t = tg; t < 256; t += 4)
    acc += cw[t] * (float)Ob[(size_t)t * HD_ + d];
  sm[tid] = acc;
  __syncthreads();
  if (tid < 64) {
    float s = sm[tid] + sm[tid + 64] + sm[tid + 128] + sm[tid + 192];
    atomicAdd(&pre[b * D_ + h * 64 + tid], s * (1.f / 32768.f));
  }
}

// ---------------------------------------------------------------------------
// out_acc: out[b,d] += sum_{k in chunk} pre[b,k]*Wo[k,d]  (+bo[d] on chunk 0)
// d_out memset to 0 beforehand. 128 blocks = 4 d-chunks x 32 k-chunks.
// ---------------------------------------------------------------------------
__global__ __launch_bounds__(256) void out_acc(
    const float* __restrict__ pre, const float* __restrict__ Wo,
    const float* __restrict__ bo, float* __restrict__ out)
{
  const int dc = blockIdx.x & 3, kb = blockIdx.x >> 2;
  const int d = dc * 256 + threadIdx.x;
  const int k0 = kb * 32;
  float acc0 = 0.f, acc1 = 0.f, acc2 = 0.f, acc3 = 0.f;
#pragma unroll
  for (int kk = 0; kk < 32; ++kk) {
    const int k = k0 + kk;
    const float w = Wo[(size_t)k * D_ + d];
    acc0 = fmaf(pre[k],            w, acc0);
    acc1 = fmaf(pre[D_ + k],       w, acc1);
    acc2 = fmaf(pre[2 * D_ + k],   w, acc2);
    acc3 = fmaf(pre[3 * D_ + k],   w, acc3);
  }
  if (kb == 0) {
    const float bd = bo[d];
    acc0 += bd; acc1 += bd; acc2 += bd; acc3 += bd;
  }
  atomicAdd(&out[d],           acc0);
  atomicAdd(&out[D_ + d],      acc1);
  atomicAdd(&out[2 * D_ + d],  acc2);
  atomicAdd(&out[3 * D_ + d],  acc3);
}

// ---------------------------------------------------------------------------
extern "C" void kernel_launch(void* const* d_in, const int* in_sizes, int n_in,
                              void* d_out, int out_size, void* d_ws, size_t ws_size,
                              hipStream_t stream)
{
  (void)in_sizes; (void)n_in; (void)out_size;
  const float* x  = (const float*)d_in[0];
  const float* Wq = (const float*)d_in[1];
  const float* bq = (const float*)d_in[2];
  const float* Wk = (const float*)d_in[3];
  const float* bk = (const float*)d_in[4];
  const float* Wv = (const float*)d_in[5];
  const float* bv = (const float*)d_in[6];
  const float* Wo = (const float*)d_in[7];
  const float* bo = (const float*)d_in[8];
  float* out = (float*)d_out;

  char* ws = (char*)d_ws;
  const size_t MB = 1ull << 20;
  bf16_t* Qw  = (bf16_t*)(ws);
  bf16_t* Kw  = (bf16_t*)(ws + 16 * MB);
  bf16_t* Vtw = (bf16_t*)(ws + 32 * MB);
  bf16_t* XO  = (bf16_t*)(ws + 48 * MB);   // xb during GEMMs, O during attn
  const size_t need_fast = 72 * MB;
  const bool fast = ws_size >= need_fast;

  float* LV;   // Linv [64][2048] f32 = 512 KB
  float* CS;   // colsum [4][2048] f32 = 32 KB
  float* PRE;  // pre [4][1024] f32 = 16 KB (contiguous after CS)
  dim3 blk(256, 1, 1);

  if (fast) {
    bf16_t* WtAll = (bf16_t*)(ws + 64 * MB);  // [3072][1024] bf16 = 6 MB
    LV  = (float*)(ws + 70 * MB);
    CS  = (float*)(ws + 70 * MB + 512 * 1024);
    PRE = (float*)(ws + 70 * MB + 512 * 1024 + 32 * 1024);
    conv_x<<<dim3((B_ * T_ * D_) / (256 * 8), 1, 1), blk, 0, stream>>>(x, XO);
    conv_wt3<<<dim3(16, 16, 3), blk, 0, stream>>>(Wq, Wk, Wv, WtAll);
    gemm_qkv<<<dim3(1536, 1, 1), blk, 0, stream>>>(XO, WtAll, bq, bk, bv,
                                                   Qw, Kw, Vtw);
  } else {
    LV  = (float*)(ws + 64 * MB);
    CS  = (float*)(ws + 64 * MB + 512 * 1024);
    PRE = (float*)(ws + 64 * MB + 512 * 1024 + 32 * 1024);
    qkv_gemm_f32<0><<<dim3(8, 64, 1), blk, 0, stream>>>(x, Wq, bq, Qw, QSCALE);
    qkv_gemm_f32<0><<<dim3(8, 64, 1), blk, 0, stream>>>(x, Wk, bk, Kw, 1.0f);
    qkv_gemm_f32<1><<<dim3(8, 64, 1), blk, 0, stream>>>(x, Wv, bv, Vtw, 1.0f);
  }

  // CS and PRE are contiguous: one memset covers both
  hipMemsetAsync(CS, 0, (size_t)(B_ * T_ + B_ * D_) * sizeof(float), stream);
  hipMemsetAsync(out, 0, (size_t)B_ * D_ * sizeof(float), stream);

  attnA<<<dim3(1024, 1, 1), blk, 0, stream>>>(Qw, Kw, Vtw, XO, LV);
  attnB<<<dim3(1024, 1, 1), blk, 0, stream>>>(Qw, Kw, LV, CS);
  pool3<<<dim3(512, 1, 1), blk, 0, stream>>>(XO, CS, PRE);
  out_acc<<<dim3(128, 1, 1), blk, 0, stream>>>(PRE, Wo, bo, out);
}

// Round 11
// 305.967 us; speedup vs baseline: 1.2448x; 1.2448x over previous
//
#include <hip/hip_runtime.h>
#include <hip/hip_bf16.h>
#include <stdint.h>

#define B_ 4
#define T_ 2048
#define D_ 1024
#define H_ 16
#define HD_ 64

// softmax computed as 2^(s*log2e): log2(e)/8 folded into Q projection scale
#define QSCALE 0.1803368801111244f

typedef __bf16 bf16_t;
typedef __bf16 bf16x8 __attribute__((ext_vector_type(8)));
typedef __bf16 bf16x4 __attribute__((ext_vector_type(4)));
typedef float f32x4 __attribute__((ext_vector_type(4)));

__device__ __forceinline__ f32x4 mfma16(bf16x8 a, bf16x8 b, f32x4 c) {
  return __builtin_amdgcn_mfma_f32_16x16x32_bf16(a, b, c, 0, 0, 0);
}

__device__ __forceinline__ void gload_lds16(const bf16_t* g, bf16_t* l) {
  __builtin_amdgcn_global_load_lds(
      (const __attribute__((address_space(1))) unsigned int*)g,
      (__attribute__((address_space(3))) unsigned int*)l, 16, 0, 0);
}

__device__ __forceinline__ float exp2g(float x) {
  return __builtin_amdgcn_exp2f(x);
}

// ---------------------------------------------------------------------------
// convert x fp32 -> bf16 (linear)
// ---------------------------------------------------------------------------
__global__ __launch_bounds__(256) void conv_x(const float* __restrict__ x,
                                              bf16_t* __restrict__ xb) {
  size_t i = ((size_t)blockIdx.x * 256 + threadIdx.x) * 8;
  float4 a = *(const float4*)(x + i);
  float4 b = *(const float4*)(x + i + 4);
  bf16x8 v;
  v[0] = (bf16_t)a.x; v[1] = (bf16_t)a.y; v[2] = (bf16_t)a.z; v[3] = (bf16_t)a.w;
  v[4] = (bf16_t)b.x; v[5] = (bf16_t)b.y; v[6] = (bf16_t)b.z; v[7] = (bf16_t)b.w;
  *(bf16x8*)(xb + i) = v;
}

// ---------------------------------------------------------------------------
// convert + transpose W[k][n] fp32 -> Wt[n][k] bf16 (64x64 tiles via LDS)
// blockIdx.z selects which of the 3 weight matrices (one launch).
// ---------------------------------------------------------------------------
__global__ __launch_bounds__(256) void conv_wt3(
    const float* __restrict__ Wq, const float* __restrict__ Wk,
    const float* __restrict__ Wv, bf16_t* __restrict__ WtAll) {
  __shared__ float Ls[64][65];
  const int tid = threadIdx.x;
  const int z = blockIdx.z;
  const float* W = (z == 0) ? Wq : (z == 1) ? Wk : Wv;
  bf16_t* Wt = WtAll + (size_t)z * 1024 * D_;
  const int k0 = blockIdx.y * 64, n0 = blockIdx.x * 64;
  const int rr = tid >> 4, cc = (tid & 15) * 4;
#pragma unroll
  for (int it = 0; it < 4; ++it) {
    int r = rr + it * 16;
    float4 v = *(const float4*)(W + (size_t)(k0 + r) * D_ + n0 + cc);
    Ls[r][cc] = v.x; Ls[r][cc + 1] = v.y; Ls[r][cc + 2] = v.z; Ls[r][cc + 3] = v.w;
  }
  __syncthreads();
#pragma unroll
  for (int it = 0; it < 4; ++it) {
    int nl = rr + it * 16;
    bf16x4 o;
    o[0] = (bf16_t)Ls[cc][nl];     o[1] = (bf16_t)Ls[cc + 1][nl];
    o[2] = (bf16_t)Ls[cc + 2][nl]; o[3] = (bf16_t)Ls[cc + 3][nl];
    *(bf16x4*)(Wt + (size_t)(n0 + nl) * D_ + k0 + cc) = o;
  }
}

// ---------------------------------------------------------------------------
// fused QKV GEMM: A=xb[8192][1024], Bt=WtAll[3072][1024]. 128x128 tiles,
// BK=64, global_load_lds staging. 1536 blocks. XCD map v2: mb-FASTEST within
// each XCD slice (mb = xcd*8 + local%8, nb = local/8) so the ~96 concurrent
// blocks per XCD span 8 mb x 12 nb -> L2 window = A 2MB + B 3MB (fits),
// instead of n-fastest's 6MB B-window that thrashed (FETCH 160MB).
// mode = nb>>3: 0->Q (scaled QSCALE), 1->K, 2->V transposed.
// ---------------------------------------------------------------------------
__global__ __launch_bounds__(256) void gemm_qkv(
    const bf16_t* __restrict__ A, const bf16_t* __restrict__ Bt,
    const float* __restrict__ bq, const float* __restrict__ bk,
    const float* __restrict__ bv,
    bf16_t* __restrict__ Qo, bf16_t* __restrict__ Ko, bf16_t* __restrict__ Vo)
{
  __shared__ __align__(16) bf16_t As[128 * 64];
  __shared__ __align__(16) bf16_t Bs[128 * 64];
  const int tid = threadIdx.x, lane = tid & 63, wv = tid >> 6;
  const int wr = wv >> 1, wc = wv & 1;
  const int wg = blockIdx.x;
  const int xcd = wg & 7;
  const int local = wg >> 3;                    // 0..191
  const int mb = xcd * 8 + (local & 7);         // 64 mb, 8 per XCD
  const int nb = local >> 3;                    // 0..23
  const int m0 = mb * 128, n0 = nb * 128;
  const int mode = nb >> 3;                     // 0..2
  const int lr = lane & 15, lg = lane >> 4;
  const int srow = wv * 8 + (lane >> 3);
  const int scol = (lane & 7) * 8;

  f32x4 acc[4][4] = {};

  for (int k0 = 0; k0 < D_; k0 += 64) {
    __syncthreads();
#pragma unroll
    for (int i = 0; i < 4; ++i) {
      gload_lds16(A + (size_t)(m0 + i * 32 + srow) * D_ + k0 + scol,
                  &As[(i * 32 + wv * 8) * 64]);
      gload_lds16(Bt + (size_t)(n0 + i * 32 + srow) * D_ + k0 + scol,
                  &Bs[(i * 32 + wv * 8) * 64]);
    }
    __syncthreads();

#pragma unroll
    for (int ks = 0; ks < 2; ++ks) {
      bf16x8 af[4], bfr[4];
#pragma unroll
      for (int i = 0; i < 4; ++i)
        af[i] = *(const bf16x8*)&As[(wr * 64 + i * 16 + lr) * 64 + ks * 32 + lg * 8];
#pragma unroll
      for (int j = 0; j < 4; ++j)
        bfr[j] = *(const bf16x8*)&Bs[(wc * 64 + j * 16 + lr) * 64 + ks * 32 + lg * 8];
      if (mode < 2) {
#pragma unroll
        for (int i = 0; i < 4; ++i)
#pragma unroll
          for (int j = 0; j < 4; ++j)
            acc[i][j] = mfma16(af[i], bfr[j], acc[i][j]);
      } else {
#pragma unroll
        for (int i = 0; i < 4; ++i)
#pragma unroll
          for (int j = 0; j < 4; ++j)
            acc[i][j] = mfma16(bfr[j], af[i], acc[i][j]);
      }
    }
  }

  if (mode == 2) {
    const int nl0 = n0 - 2048;
#pragma unroll
    for (int i = 0; i < 4; ++i) {
      int m = m0 + wr * 64 + i * 16 + lr;
      int b = m >> 11, t = m & (T_ - 1);
#pragma unroll
      for (int j = 0; j < 4; ++j)
#pragma unroll
        for (int r = 0; r < 4; ++r) {
          int n = nl0 + wc * 64 + j * 16 + lg * 4 + r;
          int h = n >> 6, d = n & 63;
          float val = acc[i][j][r] + bv[n];
          Vo[((size_t)(b * H_ + h) * HD_ + d) * T_ + t] = (bf16_t)val;
        }
    }
  } else {
    bf16_t* out = mode ? Ko : Qo;
    const float* bias = mode ? bk : bq;
    const float scale = mode ? 1.0f : QSCALE;
    const int nl0 = n0 - mode * 1024;
#pragma unroll
    for (int j = 0; j < 4; ++j) {
      int n = nl0 + wc * 64 + j * 16 + lr;
      float bval = bias[n];
      int h = n >> 6, d = n & 63;
#pragma unroll
      for (int i = 0; i < 4; ++i)
#pragma unroll
        for (int r = 0; r < 4; ++r) {
          int m = m0 + wr * 64 + i * 16 + lg * 4 + r;
          int b = m >> 11, t = m & (T_ - 1);
          float val = (acc[i][j][r] + bval) * scale;
          out[(((size_t)(b * H_ + h)) * T_ + t) * HD_ + d] = (bf16_t)val;
        }
    }
  }
}

// ---------------------------------------------------------------------------
// fallback GEMM (fp32 inputs) — validated round-1/2 structure
// ---------------------------------------------------------------------------
template <int OUT_MODE>
__global__ __launch_bounds__(256) void qkv_gemm_f32(
    const float* __restrict__ x, const float* __restrict__ W,
    const float* __restrict__ bias, bf16_t* __restrict__ out, float scale)
{
  __shared__ bf16_t As[128][40];
  __shared__ bf16_t Bs[128][40];
  const int tid = threadIdx.x, lane = tid & 63, wv = tid >> 6;
  const int wr = wv >> 1, wc = wv & 1;
  const int m0 = blockIdx.y * 128, n0 = blockIdx.x * 128;
  const int lr = lane & 15, lg = lane >> 4;
  f32x4 acc[4][4] = {};
  const int xr = tid >> 3, xc = tid & 7;
  const int wk = tid >> 5, wn = tid & 31;

  for (int k0 = 0; k0 < D_; k0 += 32) {
    __syncthreads();
#pragma unroll
    for (int it = 0; it < 4; ++it) {
      int r = xr + it * 32;
      float4 v = *(const float4*)(x + (size_t)(m0 + r) * D_ + k0 + xc * 4);
      bf16_t* dst = &As[r][xc * 4];
      dst[0] = (bf16_t)v.x; dst[1] = (bf16_t)v.y;
      dst[2] = (bf16_t)v.z; dst[3] = (bf16_t)v.w;
    }
#pragma unroll
    for (int it = 0; it < 4; ++it) {
      int k = wk + it * 8;
      float4 v = *(const float4*)(W + (size_t)(k0 + k) * D_ + n0 + wn * 4);
      Bs[wn * 4 + 0][k] = (bf16_t)v.x;
      Bs[wn * 4 + 1][k] = (bf16_t)v.y;
      Bs[wn * 4 + 2][k] = (bf16_t)v.z;
      Bs[wn * 4 + 3][k] = (bf16_t)v.w;
    }
    __syncthreads();
    bf16x8 af[4], bfr[4];
#pragma unroll
    for (int i = 0; i < 4; ++i) af[i]  = *(const bf16x8*)&As[wr * 64 + i * 16 + lr][lg * 8];
#pragma unroll
    for (int j = 0; j < 4; ++j) bfr[j] = *(const bf16x8*)&Bs[wc * 64 + j * 16 + lr][lg * 8];
#pragma unroll
    for (int i = 0; i < 4; ++i)
#pragma unroll
      for (int j = 0; j < 4; ++j) {
        if (OUT_MODE == 0) acc[i][j] = mfma16(af[i], bfr[j], acc[i][j]);
        else               acc[i][j] = mfma16(bfr[j], af[i], acc[i][j]);
      }
  }

  if (OUT_MODE == 0) {
#pragma unroll
    for (int j = 0; j < 4; ++j) {
      int n = n0 + wc * 64 + j * 16 + lr;
      float bval = bias[n];
      int h = n >> 6, d = n & 63;
#pragma unroll
      for (int i = 0; i < 4; ++i)
#pragma unroll
        for (int r = 0; r < 4; ++r) {
          int m = m0 + wr * 64 + i * 16 + lg * 4 + r;
          int b = m >> 11, t = m & (T_ - 1);
          float val = (acc[i][j][r] + bval) * scale;
          out[(((size_t)(b * H_ + h)) * T_ + t) * HD_ + d] = (bf16_t)val;
        }
    }
  } else {
#pragma unroll
    for (int i = 0; i < 4; ++i) {
      int m = m0 + wr * 64 + i * 16 + lr;
      int b = m >> 11, t = m & (T_ - 1);
#pragma unroll
      for (int j = 0; j < 4; ++j)
#pragma unroll
        for (int r = 0; r < 4; ++r) {
          int n = n0 + wc * 64 + j * 16 + lg * 4 + r;
          int h = n >> 6, d = n & 63;
          float val = acc[i][j][r] + bias[n];
          out[((size_t)(b * H_ + h) * HD_ + d) * T_ + t] = (bf16_t)val;
        }
    }
  }
}

// ---------------------------------------------------------------------------
// attnA v5 (round-9, best measured): pair-processed, P ping-pong.
// Block = (bh, 128 q), 4 waves x 32 q. Two 64-row K-tiles per barrier
// (4-buffer K rotation); each tile of the pair uses its OWN per-wave P
// buffer so the two chains are independent. V direct from global Vt[d][t].
// ---------------------------------------------------------------------------
__global__ __launch_bounds__(256, 2) void attnA(
    const bf16_t* __restrict__ Q, const bf16_t* __restrict__ K,
    const bf16_t* __restrict__ Vt, bf16_t* __restrict__ O,
    float* __restrict__ Linv)
{
  __shared__ __align__(16) bf16_t Ks[4][64 * 64];     // 32 KB, pair-rotated
  __shared__ __align__(16) bf16_t Pl[4][2][32 * 64];  // 32 KB, ping-pong
  __shared__ float ltab[4][32];

  const int tid = threadIdx.x, lane = tid & 63, wv = tid >> 6;
  const int lr = lane & 15, lg = lane >> 4;
  // 1024 blocks = 8 xcd * 8 bh * 16 qb
  const int wg = blockIdx.x;
  const int p_ = wg >> 3;
  const int bh = (wg & 7) * 8 + (p_ >> 4);
  const int qb = p_ & 15;
  const int q0 = qb * 128 + wv * 32;
  const int swz = (lr & 7) << 3;
  const int kswz = lr & 7;

  const bf16_t* Qb = Q + (size_t)bh * T_ * HD_;
  const bf16_t* Kb = K + (size_t)bh * T_ * HD_;
  const bf16_t* Vb = Vt + (size_t)bh * HD_ * T_;

  bf16x8 qf0[2], qf1[2];
#pragma unroll
  for (int ks = 0; ks < 2; ++ks) {
    qf0[ks] = *(const bf16x8*)(Qb + (size_t)(q0 + lr) * HD_ + ks * 32 + lg * 8);
    qf1[ks] = *(const bf16x8*)(Qb + (size_t)(q0 + 16 + lr) * HD_ + ks * 32 + lg * 8);
  }

  auto stageK = [&](int buf, int t0) {
    const bf16_t* src = Kb + (size_t)t0 * HD_;
#pragma unroll
    for (int rnd = 0; rnd < 2; ++rnd) {
      const int c = rnd * 256 + tid;
      const int row = c >> 3;
      const int sc16 = (c & 7) ^ (row & 7);
      gload_lds16(src + row * HD_ + sc16 * 8, &Ks[buf][c * 8]);
    }
  };

  float lacc0 = 0.f, lacc1 = 0.f;
  f32x4 oacc[2][4] = {};

  auto computeTile = [&](const bf16_t* Kl, int t0, bf16_t* Pw) {
    // V fragments: issue early, consumed by PV at tile end
    bf16x8 vfa[4], vfb[4];
#pragma unroll
    for (int dj = 0; dj < 4; ++dj) {
      vfa[dj] = *(const bf16x8*)(Vb + (size_t)(dj * 16 + lr) * T_ + t0 + lg * 8);
      vfb[dj] = *(const bf16x8*)(Vb + (size_t)(dj * 16 + lr) * T_ + t0 + 32 + lg * 8);
    }
#pragma unroll
    for (int tt = 0; tt < 4; ++tt) {
      const int row = tt * 16 + lr;
      bf16x8 kf0 = *(const bf16x8*)&Kl[row * 64 + ((lg ^ kswz) * 8)];
      bf16x8 kf1 = *(const bf16x8*)&Kl[row * 64 + (((4 + lg) ^ kswz) * 8)];
      f32x4 s0 = {}, s1 = {};
      __builtin_amdgcn_s_setprio(1);
      s0 = mfma16(kf0, qf0[0], s0);
      s0 = mfma16(kf1, qf0[1], s0);
      s1 = mfma16(kf0, qf1[0], s1);
      s1 = mfma16(kf1, qf1[1], s1);
      __builtin_amdgcn_s_setprio(0);
      f32x4 e0, e1;
#pragma unroll
      for (int r = 0; r < 4; ++r) {
        e0[r] = exp2g(s0[r]);
        e1[r] = exp2g(s1[r]);
        lacc0 += e0[r];
        lacc1 += e1[r];
      }
      const int tb = tt * 16 + lg * 4;
      bf16x4 pk0, pk1;
#pragma unroll
      for (int r = 0; r < 4; ++r) { pk0[r] = (bf16_t)e0[r]; pk1[r] = (bf16_t)e1[r]; }
      *(bf16x4*)&Pw[(lr) * 64 + (tb ^ swz)]      = pk0;
      *(bf16x4*)&Pw[(16 + lr) * 64 + (tb ^ swz)] = pk1;
    }

    bf16x8 pf0[2], pf1[2];
#pragma unroll
    for (int ks = 0; ks < 2; ++ks) {
      pf0[ks] = *(const bf16x8*)&Pw[(lr) * 64 + ((ks * 32 + lg * 8) ^ swz)];
      pf1[ks] = *(const bf16x8*)&Pw[(16 + lr) * 64 + ((ks * 32 + lg * 8) ^ swz)];
    }
    __builtin_amdgcn_s_setprio(1);
#pragma unroll
    for (int dj = 0; dj < 4; ++dj) {
      oacc[0][dj] = mfma16(pf0[0], vfa[dj], oacc[0][dj]);
      oacc[0][dj] = mfma16(pf0[1], vfb[dj], oacc[0][dj]);
      oacc[1][dj] = mfma16(pf1[0], vfa[dj], oacc[1][dj]);
      oacc[1][dj] = mfma16(pf1[1], vfb[dj], oacc[1][dj]);
    }
    __builtin_amdgcn_s_setprio(0);
  };

  // prologue: stage pair 0
  stageK(0, 0);
  stageK(1, 64);
  __syncthreads();

  for (int p = 0; p < 16; ++p) {
    const int base = (p & 1) ? 2 : 0;
    const int other = base ^ 2;
    if (p < 15) {
      stageK(other,     (2 * p + 2) * 64);
      stageK(other + 1, (2 * p + 3) * 64);
    }
    computeTile(&Ks[base][0],     (2 * p) * 64,     &Pl[wv][0][0]);
    computeTile(&Ks[base + 1][0], (2 * p + 1) * 64, &Pl[wv][1][0]);
    __syncthreads();
  }

  // reduce l over the 4 lane-groups sharing q = lr (+16)
  lacc0 += __shfl_xor(lacc0, 16); lacc0 += __shfl_xor(lacc0, 32);
  lacc1 += __shfl_xor(lacc1, 16); lacc1 += __shfl_xor(lacc1, 32);
  const float linv0 = 1.f / lacc0, linv1 = 1.f / lacc1;
  if (lg == 0) {
    ltab[wv][lr] = linv0;
    ltab[wv][16 + lr] = linv1;
    Linv[(size_t)bh * T_ + q0 + lr] = linv0;
    Linv[(size_t)bh * T_ + q0 + 16 + lr] = linv1;
  }
  __syncthreads();

  // normalize + write O[bh, q, d]
#pragma unroll
  for (int qi = 0; qi < 2; ++qi)
#pragma unroll
    for (int dj = 0; dj < 4; ++dj)
#pragma unroll
      for (int r = 0; r < 4; ++r) {
        int ql = qi * 16 + lg * 4 + r;
        float sc = ltab[wv][ql];
        O[((size_t)bh * T_ + q0 + ql) * HD_ + dj * 16 + lr] =
            (bf16_t)(oacc[qi][dj][r] * sc);
      }
}

// ---------------------------------------------------------------------------
// attnB: colsum[b,t] += sum_q 2^(s[q,t]) * Linv[q]  (per head, atomic).
// 1024 blocks = 64 bh x 8 tc x 2 q-splits. K rows in registers. No LDS.
// ---------------------------------------------------------------------------
__global__ __launch_bounds__(256) void attnB(
    const bf16_t* __restrict__ Q, const bf16_t* __restrict__ K,
    const float* __restrict__ Linv, float* __restrict__ colsum)
{
  const int tid = threadIdx.x, lane = tid & 63, wv = tid >> 6;
  const int lr = lane & 15, lg = lane >> 4;
  // 1024 blocks = 8 xcd * 8 bh * (8 tc * 2 qs)
  const int wg = blockIdx.x;
  const int p_ = wg >> 3;
  const int bh = (wg & 7) * 8 + (p_ >> 4);
  const int rem = p_ & 15;
  const int tc = rem >> 1;
  const int qs = rem & 1;
  const int b = bh >> 4;
  const int t0w = tc * 256 + wv * 64;

  const bf16_t* Qb = Q + (size_t)bh * T_ * HD_;
  const bf16_t* Kb = K + (size_t)bh * T_ * HD_;
  const float* Lb = Linv + (size_t)bh * T_;

  bf16x8 kf[4][2];
#pragma unroll
  for (int tt = 0; tt < 4; ++tt)
#pragma unroll
    for (int ks = 0; ks < 2; ++ks)
      kf[tt][ks] = *(const bf16x8*)(Kb + (size_t)(t0w + tt * 16 + lr) * HD_ +
                                    ks * 32 + lg * 8);

  float acc[4][4] = {};   // [tt][r] : t = t0w + tt*16 + 4*lg + r

  const int qlo = qs * (T_ / 2), qhi = qlo + T_ / 2;
  for (int qb = qlo; qb < qhi; qb += 64) {
#pragma unroll
    for (int qt = 0; qt < 4; ++qt) {
      const int q = qb + qt * 16 + lr;
      bf16x8 qv0 = *(const bf16x8*)(Qb + (size_t)q * HD_ + lg * 8);
      bf16x8 qv1 = *(const bf16x8*)(Qb + (size_t)q * HD_ + 32 + lg * 8);
      const float lv = Lb[q];
#pragma unroll
      for (int tt = 0; tt < 4; ++tt) {
        f32x4 s = {};
        __builtin_amdgcn_s_setprio(1);
        s = mfma16(kf[tt][0], qv0, s);
        s = mfma16(kf[tt][1], qv1, s);
        __builtin_amdgcn_s_setprio(0);
#pragma unroll
        for (int r = 0; r < 4; ++r)
          acc[tt][r] = fmaf(exp2g(s[r]), lv, acc[tt][r]);
      }
    }
  }

#pragma unroll
  for (int tt = 0; tt < 4; ++tt)
#pragma unroll
    for (int r = 0; r < 4; ++r) {
      float v = acc[tt][r];
      v += __shfl_xor(v, 1); v += __shfl_xor(v, 2);
      v += __shfl_xor(v, 4); v += __shfl_xor(v, 8);
      acc[tt][r] = v;
    }
  if (lr == 0) {
#pragma unroll
    for (int tt = 0; tt < 4; ++tt)
#pragma unroll
      for (int r = 0; r < 4; ++r)
        atomicAdd(&colsum[b * T_ + t0w + tt * 16 + lg * 4 + r], acc[tt][r]);
  }
}

// ---------------------------------------------------------------------------
// pooling: pre[b, h*64+d] += (1/32768) * sum_{t in chunk} CS[b,t] * O[bh,t,d]
// 512 blocks = 64 bh x 8 t-chunks; PRE zeroed beforehand.
// ---------------------------------------------------------------------------
__global__ __launch_bounds__(256) void pool3(
    const bf16_t* __restrict__ O, const float* __restrict__ CS,
    float* __restrict__ pre)
{
  __shared__ float sm[256];
  const int wg = blockIdx.x;
  const int bh = wg >> 3, tc = wg & 7;
  const int b = bh >> 4, h = bh & 15;
  const int tid = threadIdx.x, d = tid & 63, tg = tid >> 6;
  const bf16_t* Ob = O + (size_t)bh * T_ * HD_ + (size_t)tc * 256 * HD_;
  const float* cw = CS + b * T_ + tc * 256;
  float acc = 0.f;
  for (int t = tg; t < 256; t += 4)
    acc += cw[t] * (float)Ob[(size_t)t * HD_ + d];
  sm[tid] = acc;
  __syncthreads();
  if (tid < 64) {
    float s = sm[tid] + sm[tid + 64] + sm[tid + 128] + sm[tid + 192];
    atomicAdd(&pre[b * D_ + h * 64 + tid], s * (1.f / 32768.f));
  }
}

// ---------------------------------------------------------------------------
// out_acc: out[b,d] += sum_{k in chunk} pre[b,k]*Wo[k,d]  (+bo[d] on chunk 0)
// d_out memset to 0 beforehand. 128 blocks = 4 d-chunks x 32 k-chunks.
// ---------------------------------------------------------------------------
__global__ __launch_bounds__(256) void out_acc(
    const float* __restrict__ pre, const float* __restrict__ Wo,
    const float* __restrict__ bo, float* __restrict__ out)
{
  const int dc = blockIdx.x & 3, kb = blockIdx.x >> 2;
  const int d = dc * 256 + threadIdx.x;
  const int k0 = kb * 32;
  float acc0 = 0.f, acc1 = 0.f, acc2 = 0.f, acc3 = 0.f;
#pragma unroll
  for (int kk = 0; kk < 32; ++kk) {
    const int k = k0 + kk;
    const float w = Wo[(size_t)k * D_ + d];
    acc0 = fmaf(pre[k],            w, acc0);
    acc1 = fmaf(pre[D_ + k],       w, acc1);
    acc2 = fmaf(pre[2 * D_ + k],   w, acc2);
    acc3 = fmaf(pre[3 * D_ + k],   w, acc3);
  }
  if (kb == 0) {
    const float bd = bo[d];
    acc0 += bd; acc1 += bd; acc2 += bd; acc3 += bd;
  }
  atomicAdd(&out[d],           acc0);
  atomicAdd(&out[D_ + d],      acc1);
  atomicAdd(&out[2 * D_ + d],  acc2);
  atomicAdd(&out[3 * D_ + d],  acc3);
}

// ---------------------------------------------------------------------------
extern "C" void kernel_launch(void* const* d_in, const int* in_sizes, int n_in,
                              void* d_out, int out_size, void* d_ws, size_t ws_size,
                              hipStream_t stream)
{
  (void)in_sizes; (void)n_in; (void)out_size;
  const float* x  = (const float*)d_in[0];
  const float* Wq = (const float*)d_in[1];
  const float* bq = (const float*)d_in[2];
  const float* Wk = (const float*)d_in[3];
  const float* bk = (const float*)d_in[4];
  const float* Wv = (const float*)d_in[5];
  const float* bv = (const float*)d_in[6];
  const float* Wo = (const float*)d_in[7];
  const float* bo = (const float*)d_in[8];
  float* out = (float*)d_out;

  char* ws = (char*)d_ws;
  const size_t MB = 1ull << 20;
  bf16_t* Qw  = (bf16_t*)(ws);
  bf16_t* Kw  = (bf16_t*)(ws + 16 * MB);
  bf16_t* Vtw = (bf16_t*)(ws + 32 * MB);
  bf16_t* XO  = (bf16_t*)(ws + 48 * MB);   // xb during GEMMs, O during attn
  const size_t need_fast = 72 * MB;
  const bool fast = ws_size >= need_fast;

  float* LV;   // Linv [64][2048] f32 = 512 KB
  float* CS;   // colsum [4][2048] f32 = 32 KB
  float* PRE;  // pre [4][1024] f32 = 16 KB (contiguous after CS)
  dim3 blk(256, 1, 1);

  if (fast) {
    bf16_t* WtAll = (bf16_t*)(ws + 64 * MB);  // [3072][1024] bf16 = 6 MB
    LV  = (float*)(ws + 70 * MB);
    CS  = (float*)(ws + 70 * MB + 512 * 1024);
    PRE = (float*)(ws + 70 * MB + 512 * 1024 + 32 * 1024);
    conv_x<<<dim3((B_ * T_ * D_) / (256 * 8), 1, 1), blk, 0, stream>>>(x, XO);
    conv_wt3<<<dim3(16, 16, 3), blk, 0, stream>>>(Wq, Wk, Wv, WtAll);
    gemm_qkv<<<dim3(1536, 1, 1), blk, 0, stream>>>(XO, WtAll, bq, bk, bv,
                                                   Qw, Kw, Vtw);
  } else {
    LV  = (float*)(ws + 64 * MB);
    CS  = (float*)(ws + 64 * MB + 512 * 1024);
    PRE = (float*)(ws + 64 * MB + 512 * 1024 + 32 * 1024);
    qkv_gemm_f32<0><<<dim3(8, 64, 1), blk, 0, stream>>>(x, Wq, bq, Qw, QSCALE);
    qkv_gemm_f32<0><<<dim3(8, 64, 1), blk, 0, stream>>>(x, Wk, bk, Kw, 1.0f);
    qkv_gemm_f32<1><<<dim3(8, 64, 1), blk, 0, stream>>>(x, Wv, bv, Vtw, 1.0f);
  }

  // CS and PRE are contiguous: one memset covers both
  hipMemsetAsync(CS, 0, (size_t)(B_ * T_ + B_ * D_) * sizeof(float), stream);
  hipMemsetAsync(out, 0, (size_t)B_ * D_ * sizeof(float), stream);

  attnA<<<dim3(1024, 1, 1), blk, 0, stream>>>(Qw, Kw, Vtw, XO, LV);
  attnB<<<dim3(1024, 1, 1), blk, 0, stream>>>(Qw, Kw, LV, CS);
  pool3<<<dim3(512, 1, 1), blk, 0, stream>>>(XO, CS, PRE);
  out_acc<<<dim3(128, 1, 1), blk, 0, stream>>>(PRE, Wo, bo, out);
}